// Round 4
// baseline (332.982 us; speedup 1.0000x reference)
//
#include <hip/hip_runtime.h>
#include <math.h>

// N=100000 nodes, D=128 feats, E=1600000 edges.
// f = alpha*(Ax - x) + beta*(-(x-1)*x) + clip(src*x0,-1,1)*0.1,  Ax[row] += w*x[col]
//
// R6 (resubmit after infra failure): R5 structure, tuned for build parallelism
// + gather MLP.
//  - RPB 128 (NB=782): sort grid 2x, sort LDS 22KB -> 3+ blocks/CU
//  - place EPB 4096 (391 blocks): 2x latency hiding, write amp ~3x (ok, BW is cheap)
//  - gather: unroll 4 per half-wave (8 x-row loads in flight per wave)

#define D_FEAT 128
#define RPB 128             // rows per bucket -> NB = 782
#define NB_MAX 800
#define SORT_CAP 2560       // records per bucket (mean 2048, sd ~45)
#define EPB_COUNT 8192      // edges per block in count (256 thr x 32)
#define EPB_PLACE 4096      // edges per block in place (256 thr x 16)

__device__ __forceinline__ float sigmoid_f(float v) {
    return 1.0f / (1.0f + __expf(-v));
}

__global__ void zero_kernel(int* __restrict__ p, int n) {
    int i = blockIdx.x * blockDim.x + threadIdx.x;
    if (i < n) p[i] = 0;
}

// Per-block LDS histogram of bucket ids (row>>7), flushed with no-return atomics.
__global__ __launch_bounds__(256) void count_kernel(const int* __restrict__ rows,
                                                    int* __restrict__ cnt, int E, int NB) {
    __shared__ int hist[NB_MAX];
    int t = threadIdx.x;
    for (int i = t; i < NB; i += 256) hist[i] = 0;
    __syncthreads();
    int nE4 = E >> 2;
    int base4 = blockIdx.x * (EPB_COUNT / 4);
#pragma unroll
    for (int k = 0; k < EPB_COUNT / 4 / 256; ++k) {     // 8 int4 per thread
        int i4 = base4 + k * 256 + t;
        if (i4 < nE4) {
            int4 r = ((const int4*)rows)[i4];
            atomicAdd(&hist[r.x >> 7], 1);
            atomicAdd(&hist[r.y >> 7], 1);
            atomicAdd(&hist[r.z >> 7], 1);
            atomicAdd(&hist[r.w >> 7], 1);
        }
    }
    if (blockIdx.x == 0 && t < (E & 3))                 // scalar tail
        atomicAdd(&hist[rows[(nE4 << 2) + t] >> 7], 1);
    __syncthreads();
    for (int i = t; i < NB; i += 256) {
        int c = hist[i];
        if (c) atomicAdd(&cnt[i], c);
    }
}

// One-wave exclusive scan of bucket counts -> bstart (immutable) and gcur
// (mutable reservation cursors). bstart[NB] = E.
__global__ void scan_kernel(const int* __restrict__ cnt, int* __restrict__ bstart,
                            int* __restrict__ gcur, int NB) {
    int lane = threadIdx.x;   // 64 threads
    int carry = 0;
    for (int base = 0; base < NB; base += 64) {
        int idx = base + lane;
        int v = (idx < NB) ? cnt[idx] : 0;
        int incl = v;
#pragma unroll
        for (int d = 1; d < 64; d <<= 1) {
            int tt = __shfl_up(incl, d);
            if (lane >= d) incl += tt;
        }
        int tot = __shfl(incl, 63);
        int excl = incl - v + carry;
        if (idx < NB) { bstart[idx] = excl; gcur[idx] = excl; }
        carry += tot;
    }
    if (lane == 0) bstart[NB] = carry;
}

// Bucket placement: LDS rank within (block,bucket), one atomic-return per
// (block,bucket), packed (rl<<17|col, w*alpha) records into contiguous runs.
__global__ __launch_bounds__(256) void place_kernel(const int* __restrict__ rows,
                                                    const int* __restrict__ cols,
                                                    const float* __restrict__ w,
                                                    const float* __restrict__ alpha_p,
                                                    int* __restrict__ gcur,
                                                    int2* __restrict__ raw, int E, int NB) {
    __shared__ int hist[NB_MAX];
    __shared__ int basep[NB_MAX];
    const float alpha = sigmoid_f(alpha_p[0]) * 0.1f;
    int t = threadIdx.x;
    for (int i = t; i < NB; i += 256) hist[i] = 0;
    __syncthreads();

    int base = blockIdx.x * EPB_PLACE;
#pragma unroll
    for (int k = 0; k < EPB_PLACE / 256; ++k) {
        int e = base + k * 256 + t;
        if (e < E) atomicAdd(&hist[rows[e] >> 7], 1);
    }
    __syncthreads();
    for (int i = t; i < NB; i += 256) {
        basep[i] = atomicAdd(&gcur[i], hist[i]);
        hist[i] = 0;
    }
    __syncthreads();
#pragma unroll
    for (int k = 0; k < EPB_PLACE / 256; ++k) {
        int e = base + k * 256 + t;
        if (e >= E) continue;
        int r = rows[e];
        int bkt = r >> 7;
        int rl  = r & 127;
        int rank = atomicAdd(&hist[bkt], 1);
        raw[basep[bkt] + rank] = make_int2((rl << 17) | cols[e],
                                           __float_as_int(w[e] * alpha));
    }
}

// Block-per-bucket counting sort by row-local id (128 rows). Stages the bucket
// run in LDS, builds per-row hist, scans (emitting global per-row END offsets),
// scatters sorted (col, w) records. Slow path for oversized buckets.
__global__ __launch_bounds__(256) void sort_kernel(const int2* __restrict__ raw,
                                                   int2* __restrict__ srt,
                                                   const int* __restrict__ bstart,
                                                   int* __restrict__ off, int N, int NB) {
    __shared__ int2 sbuf[SORT_CAP];     // 20 KiB
    __shared__ int hist[RPB];
    __shared__ int scanb[RPB];
    __shared__ int cursor[RPB];
    int b = blockIdx.x;
    int t = threadIdx.x;
    int bs = bstart[b], be = bstart[b + 1];
    int cntb = be - bs;
    if (t < RPB) hist[t] = 0;
    __syncthreads();

    bool fast = (cntb <= SORT_CAP);
    if (fast) {
        for (int i = t; i < cntb; i += 256) {
            int2 v = raw[bs + i];
            sbuf[i] = v;
            atomicAdd(&hist[v.x >> 17], 1);
        }
    } else {
        for (int i = t; i < cntb; i += 256)
            atomicAdd(&hist[raw[bs + i].x >> 17], 1);
    }
    __syncthreads();

    // Hillis-Steele inclusive scan over RPB=128 counts (threads 0..127).
    int v = 0;
    if (t < RPB) { v = hist[t]; scanb[t] = v; }
    __syncthreads();
    for (int d = 1; d < RPB; d <<= 1) {
        int tv = (t >= d && t < RPB) ? scanb[t - d] : 0;
        __syncthreads();
        if (t < RPB) scanb[t] += tv;
        __syncthreads();
    }
    if (t < RPB) {
        int incl = scanb[t];
        int excl = incl - v;
        int row = b * RPB + t;
        if (row < N) off[row] = bs + incl;    // END offset; start = off[row-1]
        cursor[t] = bs + excl;
    }
    __syncthreads();

    if (fast) {
        for (int i = t; i < cntb; i += 256) {
            int2 r = sbuf[i];
            int rl = r.x >> 17;
            int pos = atomicAdd(&cursor[rl], 1);
            srt[pos] = make_int2(r.x & 0x1FFFF, r.y);
        }
    } else {
        for (int i = t; i < cntb; i += 256) {
            int2 r = raw[bs + i];
            int rl = r.x >> 17;
            int pos = atomicAdd(&cursor[rl], 1);
            srt[pos] = make_int2(r.x & 0x1FFFF, r.y);
        }
    }
}

// One 64-lane wave per row; two half-waves each unrolled x4 -> 8 x-row loads in
// flight per wave. off[r] = end of row r; start = off[r-1] (0 for r=0).
__global__ void gather_kernel(const float* __restrict__ x,
                              const float* __restrict__ x0,
                              const int* __restrict__ off,
                              const int2* __restrict__ col_w,
                              const float* __restrict__ alpha_p,
                              const float* __restrict__ beta_p,
                              const float* __restrict__ src_p,
                              float* __restrict__ out, int N) {
    const float alpha = sigmoid_f(alpha_p[0]) * 0.1f;
    const float beta  = sigmoid_f(beta_p[0]) * 0.1f;
    const float src   = src_p[0];

    int gtid = blockIdx.x * blockDim.x + threadIdx.x;
    int row  = gtid >> 6;
    if (row >= N) return;
    int lane  = threadIdx.x & 63;
    int half  = lane >> 5;
    int flane = lane & 31;

    int start = (row == 0) ? 0 : off[row - 1];
    int end   = off[row];

    const float4* x4 = (const float4*)x;
    float4 a0 = make_float4(0.f, 0.f, 0.f, 0.f);
    float4 a1 = make_float4(0.f, 0.f, 0.f, 0.f);
    float4 a2 = make_float4(0.f, 0.f, 0.f, 0.f);
    float4 a3 = make_float4(0.f, 0.f, 0.f, 0.f);

    int j = start + half;
    for (; j + 6 < end; j += 8) {         // edges j, j+2, j+4, j+6 for this half
        int2 cw0 = col_w[j];
        int2 cw1 = col_w[j + 2];
        int2 cw2 = col_w[j + 4];
        int2 cw3 = col_w[j + 6];
        float4 v0 = x4[(long long)cw0.x * 32 + flane];
        float4 v1 = x4[(long long)cw1.x * 32 + flane];
        float4 v2 = x4[(long long)cw2.x * 32 + flane];
        float4 v3 = x4[(long long)cw3.x * 32 + flane];
        float w0 = __int_as_float(cw0.y);
        float w1 = __int_as_float(cw1.y);
        float w2 = __int_as_float(cw2.y);
        float w3 = __int_as_float(cw3.y);
        a0.x += w0 * v0.x; a0.y += w0 * v0.y; a0.z += w0 * v0.z; a0.w += w0 * v0.w;
        a1.x += w1 * v1.x; a1.y += w1 * v1.y; a1.z += w1 * v1.z; a1.w += w1 * v1.w;
        a2.x += w2 * v2.x; a2.y += w2 * v2.y; a2.z += w2 * v2.z; a2.w += w2 * v2.w;
        a3.x += w3 * v3.x; a3.y += w3 * v3.y; a3.z += w3 * v3.z; a3.w += w3 * v3.w;
    }
    for (; j + 2 < end; j += 4) {         // edges j, j+2
        int2 cw0 = col_w[j];
        int2 cw1 = col_w[j + 2];
        float4 v0 = x4[(long long)cw0.x * 32 + flane];
        float4 v1 = x4[(long long)cw1.x * 32 + flane];
        float w0 = __int_as_float(cw0.y);
        float w1 = __int_as_float(cw1.y);
        a0.x += w0 * v0.x; a0.y += w0 * v0.y; a0.z += w0 * v0.z; a0.w += w0 * v0.w;
        a1.x += w1 * v1.x; a1.y += w1 * v1.y; a1.z += w1 * v1.z; a1.w += w1 * v1.w;
    }
    if (j < end) {
        int2 cw = col_w[j];
        float4 v = x4[(long long)cw.x * 32 + flane];
        float wv = __int_as_float(cw.y);
        a0.x += wv * v.x; a0.y += wv * v.y; a0.z += wv * v.z; a0.w += wv * v.w;
    }
    float4 acc;
    acc.x = (a0.x + a1.x) + (a2.x + a3.x);
    acc.y = (a0.y + a1.y) + (a2.y + a3.y);
    acc.z = (a0.z + a1.z) + (a2.z + a3.z);
    acc.w = (a0.w + a1.w) + (a2.w + a3.w);

    acc.x += __shfl_xor(acc.x, 32);
    acc.y += __shfl_xor(acc.y, 32);
    acc.z += __shfl_xor(acc.z, 32);
    acc.w += __shfl_xor(acc.w, 32);

    if (half == 0) {
        long long base = (long long)row * 32 + flane;
        float4 xv  = x4[base];
        float4 x0v = ((const float4*)x0)[base];
        float xs[4]  = {xv.x, xv.y, xv.z, xv.w};
        float zs[4]  = {x0v.x, x0v.y, x0v.z, x0v.w};
        float as[4]  = {acc.x, acc.y, acc.z, acc.w};
        float os[4];
#pragma unroll
        for (int k = 0; k < 4; ++k) {
            float reaction = -(xs[k] - 1.0f) * xs[k];
            float st = fminf(fmaxf(src * zs[k], -1.0f), 1.0f);
            os[k] = as[k] - alpha * xs[k] + beta * reaction + st * 0.1f;
        }
        ((float4*)out)[base] = make_float4(os[0], os[1], os[2], os[3]);
    }
}

extern "C" void kernel_launch(void* const* d_in, const int* in_sizes, int n_in,
                              void* d_out, int out_size, void* d_ws, size_t ws_size,
                              hipStream_t stream) {
    const float* x   = (const float*)d_in[1];
    const int*   ei  = (const int*)d_in[2];
    const float* ew  = (const float*)d_in[3];
    const float* x0  = (const float*)d_in[4];
    const float* alp = (const float*)d_in[5];
    const float* bet = (const float*)d_in[6];
    const float* src = (const float*)d_in[7];
    float* out = (float*)d_out;

    const int E = in_sizes[3];
    const int N = out_size / D_FEAT;
    const int* rows = ei;
    const int* cols = ei + E;

    const int NB = (N + RPB - 1) / RPB;                    // 782
    const int nCntBlk = (E + EPB_COUNT - 1) / EPB_COUNT;   // 196
    const int nPlcBlk = (E + EPB_PLACE - 1) / EPB_PLACE;   // 391

    char* ws = (char*)d_ws;
    int* cnt    = (int*)ws;  ws += ((size_t)NB * 4 + 15) & ~15ull;
    int* bstart = (int*)ws;  ws += ((size_t)(NB + 1) * 4 + 15) & ~15ull;
    int* gcur   = (int*)ws;  ws += ((size_t)NB * 4 + 15) & ~15ull;
    int* off    = (int*)ws;  ws += ((size_t)N * 4 + 15) & ~15ull;
    int2* col_w = (int2*)ws; ws += ((size_t)E * 8 + 15) & ~15ull;

    // Raw (unsorted) records: reuse d_out as scratch (dead until gather).
    int2* raw;
    if ((size_t)out_size >= (size_t)E * 8) {
        raw = (int2*)d_out;
    } else {
        raw = (int2*)ws;     ws += ((size_t)E * 8 + 15) & ~15ull;
    }

    zero_kernel<<<(NB + 255) / 256, 256, 0, stream>>>(cnt, NB);
    count_kernel<<<nCntBlk, 256, 0, stream>>>(rows, cnt, E, NB);
    scan_kernel<<<1, 64, 0, stream>>>(cnt, bstart, gcur, NB);
    place_kernel<<<nPlcBlk, 256, 0, stream>>>(rows, cols, ew, alp, gcur, raw, E, NB);
    sort_kernel<<<NB, 256, 0, stream>>>(raw, col_w, bstart, off, N, NB);
    {
        long long threads = (long long)N * 64;
        int grid = (int)((threads + 255) / 256);
        gather_kernel<<<grid, 256, 0, stream>>>(x, x0, off, col_w, alp, bet, src, out, N);
    }
}

// Round 5
// 312.693 us; speedup vs baseline: 1.0649x; 1.0649x over previous
//
#include <hip/hip_runtime.h>
#include <math.h>

// N=100000 nodes, D=128 feats, E=1600000 edges.
// f = alpha*(Ax - x) + beta*(-(x-1)*x) + clip(src*x0,-1,1)*0.1,  Ax[row] += w*x[col]
//
// R7: gather is BW-saturated (R6 unroll was null; FETCH 430MB ~= 8 XCD x 51MB
// x-table duplication). Only lever: bytes/edge.
//  - cvt: x -> bf16 table xb (25.6MB), RNE rounding. Ax gathered from xb
//    (256B/edge instead of 512B). Epilogue stays fp32. alpha*x exact.
//  - gather: skip x0 stream when src==0 (uniform branch, bench has src=0).
//  - fallback to fp32 gather if ws can't host xb.
//  - build: R6 structure unchanged.

#define D_FEAT 128
#define RPB 128             // rows per bucket -> NB = 782
#define NB_MAX 800
#define SORT_CAP 2560       // records per bucket (mean 2048, sd ~45)
#define EPB_COUNT 8192      // edges per block in count (256 thr x 32)
#define EPB_PLACE 4096      // edges per block in place (256 thr x 16)

__device__ __forceinline__ float sigmoid_f(float v) {
    return 1.0f / (1.0f + __expf(-v));
}

__device__ __forceinline__ unsigned bf16rn(float f) {   // RNE f32->bf16 (bits)
    unsigned u = __float_as_uint(f);
    return (u + 0x7FFFu + ((u >> 16) & 1u)) >> 16;
}

__global__ void zero_kernel(int* __restrict__ p, int n) {
    int i = blockIdx.x * blockDim.x + threadIdx.x;
    if (i < n) p[i] = 0;
}

// x (f32) -> xb (bf16), 8 floats per thread.
__global__ __launch_bounds__(256) void cvt_kernel(const float* __restrict__ x,
                                                  unsigned short* __restrict__ xb,
                                                  int n8) {
    int i = blockIdx.x * 256 + threadIdx.x;
    if (i >= n8) return;
    const float4* x4 = (const float4*)x;
    float4 f0 = x4[(size_t)i * 2];
    float4 f1 = x4[(size_t)i * 2 + 1];
    uint4 o;
    o.x = bf16rn(f0.x) | (bf16rn(f0.y) << 16);
    o.y = bf16rn(f0.z) | (bf16rn(f0.w) << 16);
    o.z = bf16rn(f1.x) | (bf16rn(f1.y) << 16);
    o.w = bf16rn(f1.z) | (bf16rn(f1.w) << 16);
    ((uint4*)xb)[i] = o;
}

// Per-block LDS histogram of bucket ids (row>>7), flushed with no-return atomics.
__global__ __launch_bounds__(256) void count_kernel(const int* __restrict__ rows,
                                                    int* __restrict__ cnt, int E, int NB) {
    __shared__ int hist[NB_MAX];
    int t = threadIdx.x;
    for (int i = t; i < NB; i += 256) hist[i] = 0;
    __syncthreads();
    int nE4 = E >> 2;
    int base4 = blockIdx.x * (EPB_COUNT / 4);
#pragma unroll
    for (int k = 0; k < EPB_COUNT / 4 / 256; ++k) {     // 8 int4 per thread
        int i4 = base4 + k * 256 + t;
        if (i4 < nE4) {
            int4 r = ((const int4*)rows)[i4];
            atomicAdd(&hist[r.x >> 7], 1);
            atomicAdd(&hist[r.y >> 7], 1);
            atomicAdd(&hist[r.z >> 7], 1);
            atomicAdd(&hist[r.w >> 7], 1);
        }
    }
    if (blockIdx.x == 0 && t < (E & 3))                 // scalar tail
        atomicAdd(&hist[rows[(nE4 << 2) + t] >> 7], 1);
    __syncthreads();
    for (int i = t; i < NB; i += 256) {
        int c = hist[i];
        if (c) atomicAdd(&cnt[i], c);
    }
}

// One-wave exclusive scan of bucket counts -> bstart (immutable) and gcur
// (mutable reservation cursors). bstart[NB] = E.
__global__ void scan_kernel(const int* __restrict__ cnt, int* __restrict__ bstart,
                            int* __restrict__ gcur, int NB) {
    int lane = threadIdx.x;   // 64 threads
    int carry = 0;
    for (int base = 0; base < NB; base += 64) {
        int idx = base + lane;
        int v = (idx < NB) ? cnt[idx] : 0;
        int incl = v;
#pragma unroll
        for (int d = 1; d < 64; d <<= 1) {
            int tt = __shfl_up(incl, d);
            if (lane >= d) incl += tt;
        }
        int tot = __shfl(incl, 63);
        int excl = incl - v + carry;
        if (idx < NB) { bstart[idx] = excl; gcur[idx] = excl; }
        carry += tot;
    }
    if (lane == 0) bstart[NB] = carry;
}

// Bucket placement: LDS rank within (block,bucket), one atomic-return per
// (block,bucket), packed (rl<<17|col, w*alpha) records into contiguous runs.
__global__ __launch_bounds__(256) void place_kernel(const int* __restrict__ rows,
                                                    const int* __restrict__ cols,
                                                    const float* __restrict__ w,
                                                    const float* __restrict__ alpha_p,
                                                    int* __restrict__ gcur,
                                                    int2* __restrict__ raw, int E, int NB) {
    __shared__ int hist[NB_MAX];
    __shared__ int basep[NB_MAX];
    const float alpha = sigmoid_f(alpha_p[0]) * 0.1f;
    int t = threadIdx.x;
    for (int i = t; i < NB; i += 256) hist[i] = 0;
    __syncthreads();

    int base = blockIdx.x * EPB_PLACE;
#pragma unroll
    for (int k = 0; k < EPB_PLACE / 256; ++k) {
        int e = base + k * 256 + t;
        if (e < E) atomicAdd(&hist[rows[e] >> 7], 1);
    }
    __syncthreads();
    for (int i = t; i < NB; i += 256) {
        basep[i] = atomicAdd(&gcur[i], hist[i]);
        hist[i] = 0;
    }
    __syncthreads();
#pragma unroll
    for (int k = 0; k < EPB_PLACE / 256; ++k) {
        int e = base + k * 256 + t;
        if (e >= E) continue;
        int r = rows[e];
        int bkt = r >> 7;
        int rl  = r & 127;
        int rank = atomicAdd(&hist[bkt], 1);
        raw[basep[bkt] + rank] = make_int2((rl << 17) | cols[e],
                                           __float_as_int(w[e] * alpha));
    }
}

// Block-per-bucket counting sort by row-local id (128 rows). Stages the bucket
// run in LDS, builds per-row hist, scans (emitting global per-row END offsets),
// scatters sorted (col, w) records. Slow path for oversized buckets.
__global__ __launch_bounds__(256) void sort_kernel(const int2* __restrict__ raw,
                                                   int2* __restrict__ srt,
                                                   const int* __restrict__ bstart,
                                                   int* __restrict__ off, int N, int NB) {
    __shared__ int2 sbuf[SORT_CAP];     // 20 KiB
    __shared__ int hist[RPB];
    __shared__ int scanb[RPB];
    __shared__ int cursor[RPB];
    int b = blockIdx.x;
    int t = threadIdx.x;
    int bs = bstart[b], be = bstart[b + 1];
    int cntb = be - bs;
    if (t < RPB) hist[t] = 0;
    __syncthreads();

    bool fast = (cntb <= SORT_CAP);
    if (fast) {
        for (int i = t; i < cntb; i += 256) {
            int2 v = raw[bs + i];
            sbuf[i] = v;
            atomicAdd(&hist[v.x >> 17], 1);
        }
    } else {
        for (int i = t; i < cntb; i += 256)
            atomicAdd(&hist[raw[bs + i].x >> 17], 1);
    }
    __syncthreads();

    // Hillis-Steele inclusive scan over RPB=128 counts (threads 0..127).
    int v = 0;
    if (t < RPB) { v = hist[t]; scanb[t] = v; }
    __syncthreads();
    for (int d = 1; d < RPB; d <<= 1) {
        int tv = (t >= d && t < RPB) ? scanb[t - d] : 0;
        __syncthreads();
        if (t < RPB) scanb[t] += tv;
        __syncthreads();
    }
    if (t < RPB) {
        int incl = scanb[t];
        int excl = incl - v;
        int row = b * RPB + t;
        if (row < N) off[row] = bs + incl;    // END offset; start = off[row-1]
        cursor[t] = bs + excl;
    }
    __syncthreads();

    if (fast) {
        for (int i = t; i < cntb; i += 256) {
            int2 r = sbuf[i];
            int rl = r.x >> 17;
            int pos = atomicAdd(&cursor[rl], 1);
            srt[pos] = make_int2(r.x & 0x1FFFF, r.y);
        }
    } else {
        for (int i = t; i < cntb; i += 256) {
            int2 r = raw[bs + i];
            int rl = r.x >> 17;
            int pos = atomicAdd(&cursor[rl], 1);
            srt[pos] = make_int2(r.x & 0x1FFFF, r.y);
        }
    }
}

// bf16 gather: one 64-lane wave per row, half-wave per edge, unroll 4.
// Lane fl covers feats {4fl..4fl+3}: one uint2 (4 bf16) per edge per lane.
__global__ void gather_bf16_kernel(const float* __restrict__ x,
                                   const unsigned short* __restrict__ xb,
                                   const float* __restrict__ x0,
                                   const int* __restrict__ off,
                                   const int2* __restrict__ col_w,
                                   const float* __restrict__ alpha_p,
                                   const float* __restrict__ beta_p,
                                   const float* __restrict__ src_p,
                                   float* __restrict__ out, int N) {
    const float alpha = sigmoid_f(alpha_p[0]) * 0.1f;
    const float beta  = sigmoid_f(beta_p[0]) * 0.1f;
    const float src   = src_p[0];

    int gtid = blockIdx.x * blockDim.x + threadIdx.x;
    int row  = gtid >> 6;
    if (row >= N) return;
    int lane  = threadIdx.x & 63;
    int half  = lane >> 5;
    int flane = lane & 31;

    int start = (row == 0) ? 0 : off[row - 1];
    int end   = off[row];

    const uint2* xb2 = (const uint2*)xb;   // 32 uint2 per row
    float4 a0 = make_float4(0.f, 0.f, 0.f, 0.f);
    float4 a1 = make_float4(0.f, 0.f, 0.f, 0.f);
    float4 a2 = make_float4(0.f, 0.f, 0.f, 0.f);
    float4 a3 = make_float4(0.f, 0.f, 0.f, 0.f);

#define BF16_FMA(ACC, V, W)                                                    \
    {                                                                          \
        float b0 = __uint_as_float((V).x << 16);                               \
        float b1 = __uint_as_float((V).x & 0xFFFF0000u);                       \
        float b2 = __uint_as_float((V).y << 16);                               \
        float b3 = __uint_as_float((V).y & 0xFFFF0000u);                       \
        ACC.x += (W) * b0; ACC.y += (W) * b1;                                  \
        ACC.z += (W) * b2; ACC.w += (W) * b3;                                  \
    }

    int j = start + half;
    for (; j + 6 < end; j += 8) {         // edges j, j+2, j+4, j+6 for this half
        int2 cw0 = col_w[j];
        int2 cw1 = col_w[j + 2];
        int2 cw2 = col_w[j + 4];
        int2 cw3 = col_w[j + 6];
        uint2 v0 = xb2[(size_t)cw0.x * 32 + flane];
        uint2 v1 = xb2[(size_t)cw1.x * 32 + flane];
        uint2 v2 = xb2[(size_t)cw2.x * 32 + flane];
        uint2 v3 = xb2[(size_t)cw3.x * 32 + flane];
        float w0 = __int_as_float(cw0.y);
        float w1 = __int_as_float(cw1.y);
        float w2 = __int_as_float(cw2.y);
        float w3 = __int_as_float(cw3.y);
        BF16_FMA(a0, v0, w0);
        BF16_FMA(a1, v1, w1);
        BF16_FMA(a2, v2, w2);
        BF16_FMA(a3, v3, w3);
    }
    for (; j + 2 < end; j += 4) {         // edges j, j+2
        int2 cw0 = col_w[j];
        int2 cw1 = col_w[j + 2];
        uint2 v0 = xb2[(size_t)cw0.x * 32 + flane];
        uint2 v1 = xb2[(size_t)cw1.x * 32 + flane];
        float w0 = __int_as_float(cw0.y);
        float w1 = __int_as_float(cw1.y);
        BF16_FMA(a0, v0, w0);
        BF16_FMA(a1, v1, w1);
    }
    if (j < end) {
        int2 cw = col_w[j];
        uint2 v = xb2[(size_t)cw.x * 32 + flane];
        float wv = __int_as_float(cw.y);
        BF16_FMA(a0, v, wv);
    }
#undef BF16_FMA

    float4 acc;
    acc.x = (a0.x + a1.x) + (a2.x + a3.x);
    acc.y = (a0.y + a1.y) + (a2.y + a3.y);
    acc.z = (a0.z + a1.z) + (a2.z + a3.z);
    acc.w = (a0.w + a1.w) + (a2.w + a3.w);

    acc.x += __shfl_xor(acc.x, 32);
    acc.y += __shfl_xor(acc.y, 32);
    acc.z += __shfl_xor(acc.z, 32);
    acc.w += __shfl_xor(acc.w, 32);

    if (half == 0) {
        long long base = (long long)row * 32 + flane;
        float4 xv = ((const float4*)x)[base];
        float4 x0v = make_float4(0.f, 0.f, 0.f, 0.f);
        if (src != 0.0f)                           // uniform branch; bench src=0
            x0v = ((const float4*)x0)[base];
        float xs[4]  = {xv.x, xv.y, xv.z, xv.w};
        float zs[4]  = {x0v.x, x0v.y, x0v.z, x0v.w};
        float as[4]  = {acc.x, acc.y, acc.z, acc.w};
        float os[4];
#pragma unroll
        for (int k = 0; k < 4; ++k) {
            float reaction = -(xs[k] - 1.0f) * xs[k];
            float st = fminf(fmaxf(src * zs[k], -1.0f), 1.0f);
            os[k] = as[k] - alpha * xs[k] + beta * reaction + st * 0.1f;
        }
        ((float4*)out)[base] = make_float4(os[0], os[1], os[2], os[3]);
    }
}

// fp32 fallback gather (R6, proven) — used if ws can't host the bf16 table.
__global__ void gather_f32_kernel(const float* __restrict__ x,
                                  const float* __restrict__ x0,
                                  const int* __restrict__ off,
                                  const int2* __restrict__ col_w,
                                  const float* __restrict__ alpha_p,
                                  const float* __restrict__ beta_p,
                                  const float* __restrict__ src_p,
                                  float* __restrict__ out, int N) {
    const float alpha = sigmoid_f(alpha_p[0]) * 0.1f;
    const float beta  = sigmoid_f(beta_p[0]) * 0.1f;
    const float src   = src_p[0];

    int gtid = blockIdx.x * blockDim.x + threadIdx.x;
    int row  = gtid >> 6;
    if (row >= N) return;
    int lane  = threadIdx.x & 63;
    int half  = lane >> 5;
    int flane = lane & 31;

    int start = (row == 0) ? 0 : off[row - 1];
    int end   = off[row];

    const float4* x4 = (const float4*)x;
    float4 a0 = make_float4(0.f, 0.f, 0.f, 0.f);
    float4 a1 = make_float4(0.f, 0.f, 0.f, 0.f);

    int j = start + half;
    for (; j + 2 < end; j += 4) {
        int2 cw0 = col_w[j];
        int2 cw1 = col_w[j + 2];
        float4 v0 = x4[(long long)cw0.x * 32 + flane];
        float4 v1 = x4[(long long)cw1.x * 32 + flane];
        float w0 = __int_as_float(cw0.y);
        float w1 = __int_as_float(cw1.y);
        a0.x += w0 * v0.x; a0.y += w0 * v0.y; a0.z += w0 * v0.z; a0.w += w0 * v0.w;
        a1.x += w1 * v1.x; a1.y += w1 * v1.y; a1.z += w1 * v1.z; a1.w += w1 * v1.w;
    }
    if (j < end) {
        int2 cw = col_w[j];
        float4 v = x4[(long long)cw.x * 32 + flane];
        float wv = __int_as_float(cw.y);
        a0.x += wv * v.x; a0.y += wv * v.y; a0.z += wv * v.z; a0.w += wv * v.w;
    }
    float4 acc;
    acc.x = a0.x + a1.x; acc.y = a0.y + a1.y;
    acc.z = a0.z + a1.z; acc.w = a0.w + a1.w;

    acc.x += __shfl_xor(acc.x, 32);
    acc.y += __shfl_xor(acc.y, 32);
    acc.z += __shfl_xor(acc.z, 32);
    acc.w += __shfl_xor(acc.w, 32);

    if (half == 0) {
        long long base = (long long)row * 32 + flane;
        float4 xv  = x4[base];
        float4 x0v = make_float4(0.f, 0.f, 0.f, 0.f);
        if (src != 0.0f)
            x0v = ((const float4*)x0)[base];
        float xs[4]  = {xv.x, xv.y, xv.z, xv.w};
        float zs[4]  = {x0v.x, x0v.y, x0v.z, x0v.w};
        float as[4]  = {acc.x, acc.y, acc.z, acc.w};
        float os[4];
#pragma unroll
        for (int k = 0; k < 4; ++k) {
            float reaction = -(xs[k] - 1.0f) * xs[k];
            float st = fminf(fmaxf(src * zs[k], -1.0f), 1.0f);
            os[k] = as[k] - alpha * xs[k] + beta * reaction + st * 0.1f;
        }
        ((float4*)out)[base] = make_float4(os[0], os[1], os[2], os[3]);
    }
}

extern "C" void kernel_launch(void* const* d_in, const int* in_sizes, int n_in,
                              void* d_out, int out_size, void* d_ws, size_t ws_size,
                              hipStream_t stream) {
    const float* x   = (const float*)d_in[1];
    const int*   ei  = (const int*)d_in[2];
    const float* ew  = (const float*)d_in[3];
    const float* x0  = (const float*)d_in[4];
    const float* alp = (const float*)d_in[5];
    const float* bet = (const float*)d_in[6];
    const float* src = (const float*)d_in[7];
    float* out = (float*)d_out;

    const int E = in_sizes[3];
    const int N = out_size / D_FEAT;
    const int* rows = ei;
    const int* cols = ei + E;

    const int NB = (N + RPB - 1) / RPB;                    // 782
    const int nCntBlk = (E + EPB_COUNT - 1) / EPB_COUNT;   // 196
    const int nPlcBlk = (E + EPB_PLACE - 1) / EPB_PLACE;   // 391

    char* ws = (char*)d_ws;
    char* ws_end = (char*)d_ws + ws_size;
    int* cnt    = (int*)ws;  ws += ((size_t)NB * 4 + 15) & ~15ull;
    int* bstart = (int*)ws;  ws += ((size_t)(NB + 1) * 4 + 15) & ~15ull;
    int* gcur   = (int*)ws;  ws += ((size_t)NB * 4 + 15) & ~15ull;
    int* off    = (int*)ws;  ws += ((size_t)N * 4 + 15) & ~15ull;
    int2* col_w = (int2*)ws; ws += ((size_t)E * 8 + 15) & ~15ull;

    // Raw (unsorted) records: reuse d_out as scratch (dead until gather).
    int2* raw;
    if ((size_t)out_size >= (size_t)E * 8) {
        raw = (int2*)d_out;
    } else {
        raw = (int2*)ws;     ws += ((size_t)E * 8 + 15) & ~15ull;
    }

    // bf16 x table, if workspace permits.
    unsigned short* xb = nullptr;
    size_t xb_bytes = ((size_t)N * D_FEAT * 2 + 15) & ~15ull;
    if (ws + xb_bytes <= ws_end) {
        xb = (unsigned short*)ws;  ws += xb_bytes;
    }

    zero_kernel<<<(NB + 255) / 256, 256, 0, stream>>>(cnt, NB);
    if (xb) {
        int n8 = (N * D_FEAT) / 8;
        cvt_kernel<<<(n8 + 255) / 256, 256, 0, stream>>>(x, xb, n8);
    }
    count_kernel<<<nCntBlk, 256, 0, stream>>>(rows, cnt, E, NB);
    scan_kernel<<<1, 64, 0, stream>>>(cnt, bstart, gcur, NB);
    place_kernel<<<nPlcBlk, 256, 0, stream>>>(rows, cols, ew, alp, gcur, raw, E, NB);
    sort_kernel<<<NB, 256, 0, stream>>>(raw, col_w, bstart, off, N, NB);
    {
        long long threads = (long long)N * 64;
        int grid = (int)((threads + 255) / 256);
        if (xb)
            gather_bf16_kernel<<<grid, 256, 0, stream>>>(x, xb, x0, off, col_w,
                                                         alp, bet, src, out, N);
        else
            gather_f32_kernel<<<grid, 256, 0, stream>>>(x, x0, off, col_w,
                                                        alp, bet, src, out, N);
    }
}